// Round 3
// baseline (7661.971 us; speedup 1.0000x reference)
//
#include <hip/hip_runtime.h>
#include <hip/hip_bf16.h>

// Round 2: precision fix. fp4-quantized tensors stored as f16 hi/lo Dekker
// splits; GEMMs compute Ah*Bh + Ah*Bl + Al*Bh with f16 MFMA (effective fp32
// precision, rel err ~2^-22). Q/K/V/O and attention are full fp32, so the
// sensitive re-quantization of o sees near-exact inputs.

typedef _Float16 f16;
typedef _Float16 f16x8 __attribute__((ext_vector_type(8)));
typedef float f32x4 __attribute__((ext_vector_type(4)));

static constexpr int Bd = 2, Sd = 2048, NH = 32, HD = 64, HID = 2048;
static constexpr int Md = Bd * Sd;   // 4096

// ---------------- FP4 fake-quant (E2M1, block-16 absmax) ----------------
// searchsorted(bounds, |y|, side='left'): |y| == bound picks the LOWER grid value.
__device__ __forceinline__ float fp4_grid_round(float ay) {
  if (ay <= 0.25f) return 0.0f;
  if (ay <= 0.75f) return 0.5f;
  if (ay <= 1.25f) return 1.0f;
  if (ay <= 1.75f) return 1.5f;
  if (ay <= 2.5f)  return 2.0f;
  if (ay <= 3.5f)  return 3.0f;
  if (ay <= 5.0f)  return 4.0f;
  return 6.0f;
}

// Quantize in fp32 (exact vs reference), emit f16 hi/lo split.
__global__ __launch_bounds__(256) void quant_fp4_split_kernel(const float* __restrict__ in,
                                                              f16* __restrict__ hi,
                                                              f16* __restrict__ lo, int n4) {
  int t = blockIdx.x * 256 + threadIdx.x;
  if (t >= n4) return;
  float v[4];
#pragma unroll
  for (int i = 0; i < 4; ++i) v[i] = in[4 * t + i];
  float a = fmaxf(fmaxf(fabsf(v[0]), fabsf(v[1])), fmaxf(fabsf(v[2]), fabsf(v[3])));
  // block of 16 = 4 consecutive threads (aligned groups, never cross a wave)
  a = fmaxf(a, __shfl_xor(a, 1));
  a = fmaxf(a, __shfl_xor(a, 2));
  float scale = (a == 0.0f) ? 1.0f : (a / 6.0f);
#pragma unroll
  for (int i = 0; i < 4; ++i) {
    float y = v[i] / scale;
    float g = fp4_grid_round(fabsf(y));
    float qv = copysignf(g * scale, y);
    f16 h = (f16)qv;
    hi[4 * t + i] = h;
    lo[4 * t + i] = (f16)(qv - (float)h);
  }
}

// ---------------- split GEMM: C[M,N] = A[M,K] * B[N,K]^T --------------------
// A = Ah + Al, B = Bh + Bl (f16 splits). C ≈ Ah*Bh + Ah*Bl + Al*Bh.
// mfma_f32_16x16x32_f16 layouts (same as bf16, m89/m91-verified):
//   A frag: A[m = lane&15][k = (lane>>4)*8 + j]; C/D: row=(lane>>4)*4+r, col=lane&15
template <typename OutT>
__global__ __launch_bounds__(256) void gemm_bt32_split(const f16* __restrict__ Ah,
                                                       const f16* __restrict__ Al,
                                                       const f16* __restrict__ Bh,
                                                       const f16* __restrict__ Bl,
                                                       OutT* __restrict__ C,
                                                       int Mm, int Nn, int Kk) {
  int wave = threadIdx.x >> 6, lane = threadIdx.x & 63;
  int qd = lane >> 4, c = lane & 15;
  int it = blockIdx.x;               // Mm/32 tiles
  int jt = blockIdx.y * 4 + wave;    // Nn/32 tiles
  size_t ra0 = (size_t)(it * 32 + c) * Kk, ra1 = ra0 + (size_t)16 * Kk;
  size_t rb0 = (size_t)(jt * 32 + c) * Kk, rb1 = rb0 + (size_t)16 * Kk;
  f32x4 acc[2][2];
#pragma unroll
  for (int i = 0; i < 2; ++i)
#pragma unroll
    for (int j = 0; j < 2; ++j) acc[i][j] = f32x4{0.f, 0.f, 0.f, 0.f};
  int ko = qd * 8;
  for (int kk = 0; kk < Kk; kk += 32) {
    f16x8 ah0 = *(const f16x8*)(Ah + ra0 + kk + ko);
    f16x8 ah1 = *(const f16x8*)(Ah + ra1 + kk + ko);
    f16x8 al0 = *(const f16x8*)(Al + ra0 + kk + ko);
    f16x8 al1 = *(const f16x8*)(Al + ra1 + kk + ko);
    f16x8 bh0 = *(const f16x8*)(Bh + rb0 + kk + ko);
    f16x8 bh1 = *(const f16x8*)(Bh + rb1 + kk + ko);
    f16x8 bl0 = *(const f16x8*)(Bl + rb0 + kk + ko);
    f16x8 bl1 = *(const f16x8*)(Bl + rb1 + kk + ko);
    acc[0][0] = __builtin_amdgcn_mfma_f32_16x16x32_f16(ah0, bh0, acc[0][0], 0, 0, 0);
    acc[0][1] = __builtin_amdgcn_mfma_f32_16x16x32_f16(ah0, bh1, acc[0][1], 0, 0, 0);
    acc[1][0] = __builtin_amdgcn_mfma_f32_16x16x32_f16(ah1, bh0, acc[1][0], 0, 0, 0);
    acc[1][1] = __builtin_amdgcn_mfma_f32_16x16x32_f16(ah1, bh1, acc[1][1], 0, 0, 0);
    acc[0][0] = __builtin_amdgcn_mfma_f32_16x16x32_f16(ah0, bl0, acc[0][0], 0, 0, 0);
    acc[0][1] = __builtin_amdgcn_mfma_f32_16x16x32_f16(ah0, bl1, acc[0][1], 0, 0, 0);
    acc[1][0] = __builtin_amdgcn_mfma_f32_16x16x32_f16(ah1, bl0, acc[1][0], 0, 0, 0);
    acc[1][1] = __builtin_amdgcn_mfma_f32_16x16x32_f16(ah1, bl1, acc[1][1], 0, 0, 0);
    acc[0][0] = __builtin_amdgcn_mfma_f32_16x16x32_f16(al0, bh0, acc[0][0], 0, 0, 0);
    acc[0][1] = __builtin_amdgcn_mfma_f32_16x16x32_f16(al0, bh1, acc[0][1], 0, 0, 0);
    acc[1][0] = __builtin_amdgcn_mfma_f32_16x16x32_f16(al1, bh0, acc[1][0], 0, 0, 0);
    acc[1][1] = __builtin_amdgcn_mfma_f32_16x16x32_f16(al1, bh1, acc[1][1], 0, 0, 0);
  }
#pragma unroll
  for (int ti = 0; ti < 2; ++ti)
#pragma unroll
    for (int tj = 0; tj < 2; ++tj) {
      size_t base = (size_t)(it * 32 + ti * 16 + qd * 4) * Nn + jt * 32 + tj * 16 + c;
#pragma unroll
      for (int r = 0; r < 4; ++r) C[base + (size_t)r * Nn] = (OutT)acc[ti][tj][r];
    }
}

// ---------------- RoPE (rotate-half), in-place on fp32 Q and K --------------
__global__ __launch_bounds__(256) void rope_kernel(float* __restrict__ Q, float* __restrict__ Kb) {
  int t = blockIdx.x * 256 + threadIdx.x;   // Md * NH * 32 threads
  int d2 = t & 31;
  int h = (t >> 5) & 31;
  int sb = t >> 10;                 // b*S + s
  int s = sb & (Sd - 1);
  // inv_freq = 10000^(-d2/32) ; ln(10000)/32 = 0.2878231366242557
  float inv = expf(-0.2878231366242557f * (float)d2);
  float ang = (float)s * inv;
  float sn, cs;
  sincosf(ang, &sn, &cs);
  size_t i1 = ((size_t)sb * 32 + h) * 64 + d2;
  size_t i2 = i1 + 32;
  {
    float x1 = Q[i1], x2 = Q[i2];
    Q[i1] = x1 * cs - x2 * sn;
    Q[i2] = x2 * cs + x1 * sn;
  }
  {
    float x1 = Kb[i1], x2 = Kb[i2];
    Kb[i1] = x1 * cs - x2 * sn;
    Kb[i2] = x2 * cs + x1 * sn;
  }
}

// ---------------- Flash attention, vector fp32 ------------------------------
// wave = 64 consecutive q rows of one (b,h); lane = its own q row.
__global__ __launch_bounds__(256) void attn_kernel(const float* __restrict__ Q,
                                                   const float* __restrict__ Kb,
                                                   const float* __restrict__ V,
                                                   float* __restrict__ O) {
  int lane = threadIdx.x & 63;
  int wid = blockIdx.x * 4 + (threadIdx.x >> 6);  // 0..2047
  int qc = wid & 31;
  int h = (wid >> 5) & 31;
  int b = wid >> 10;
  int qrow = qc * 64 + lane;
  const size_t hoff = ((size_t)b * Sd * NH + h) * HD;
  const size_t rstr = (size_t)NH * HD;  // 2048

  float qreg[64];
  const float* qp = Q + hoff + (size_t)qrow * rstr;
#pragma unroll
  for (int d = 0; d < 64; ++d) qreg[d] = qp[d] * 0.125f;  // fold 1/sqrt(64)

  float Oa[64];
#pragma unroll
  for (int d = 0; d < 64; ++d) Oa[d] = 0.f;
  float m = -INFINITY, l = 0.f;

  int kmax = qc * 64 + 63;
  for (int kr = 0; kr <= kmax; ++kr) {
    float kd = Kb[hoff + (size_t)kr * rstr + lane];
    float vd = V[hoff + (size_t)kr * rstr + lane];
    float s0 = 0.f, s1 = 0.f, s2 = 0.f, s3 = 0.f;
#pragma unroll
    for (int d = 0; d < 64; d += 4) {
      s0 = fmaf(qreg[d + 0], __shfl(kd, d + 0), s0);
      s1 = fmaf(qreg[d + 1], __shfl(kd, d + 1), s1);
      s2 = fmaf(qreg[d + 2], __shfl(kd, d + 2), s2);
      s3 = fmaf(qreg[d + 3], __shfl(kd, d + 3), s3);
    }
    float s = (s0 + s1) + (s2 + s3);
    if (kr > qrow) s = -INFINITY;
    float mn = fmaxf(m, s);
    float alpha = __expf(m - mn);   // m=-inf first iter -> 0
    float p = __expf(s - mn);
    l = l * alpha + p;
    m = mn;
#pragma unroll
    for (int d = 0; d < 64; ++d) Oa[d] = fmaf(p, __shfl(vd, d), Oa[d] * alpha);
  }
  float rl = 1.f / l;
  float* op = O + hoff + (size_t)qrow * rstr;
#pragma unroll
  for (int d = 0; d < 64; ++d) op[d] = Oa[d] * rl;
}

// ---------------- launch ----------------------------------------------------
extern "C" void kernel_launch(void* const* d_in, const int* in_sizes, int n_in,
                              void* d_out, int out_size, void* d_ws, size_t ws_size,
                              hipStream_t stream) {
  (void)in_sizes; (void)n_in; (void)out_size; (void)ws_size;
  const float* x  = (const float*)d_in[0];
  const float* Wq = (const float*)d_in[1];
  const float* Wk = (const float*)d_in[2];
  const float* Wv = (const float*)d_in[3];
  const float* Wo = (const float*)d_in[4];
  float* out = (float*)d_out;   // reference output dtype is float32

  const size_t NX = (size_t)Md * HID;   // 8,388,608
  const size_t NW = (size_t)HID * HID;  // 4,194,304

  char* w = (char*)d_ws;
  size_t off = 0;
  auto alloc = [&](size_t bytes) { void* p = w + off; off += (bytes + 255) & ~(size_t)255; return p; };
  f16* xh  = (f16*)alloc(NX * 2);
  f16* xl  = (f16*)alloc(NX * 2);
  f16* wqh = (f16*)alloc(NW * 2);
  f16* wql = (f16*)alloc(NW * 2);
  f16* wkh = (f16*)alloc(NW * 2);
  f16* wkl = (f16*)alloc(NW * 2);
  f16* wvh = (f16*)alloc(NW * 2);
  f16* wvl = (f16*)alloc(NW * 2);
  f16* woh = (f16*)alloc(NW * 2);
  f16* wol = (f16*)alloc(NW * 2);
  float* qb = (float*)alloc(NX * 4);
  float* kb = (float*)alloc(NX * 4);
  float* vb = (float*)alloc(NX * 4);
  // aliases: x splits are dead after QKV gemms -> o lives there (needs NX*4 = both splits)
  float* ob = (float*)xh;
  // q is dead after attention -> o's quant splits live there
  f16* oh = (f16*)qb;
  f16* ol = oh + NX;

  const int nx4 = (int)(NX / 4);
  const int nw4 = (int)(NW / 4);
  quant_fp4_split_kernel<<<nx4 / 256, 256, 0, stream>>>(x, xh, xl, nx4);
  quant_fp4_split_kernel<<<nw4 / 256, 256, 0, stream>>>(Wq, wqh, wql, nw4);
  quant_fp4_split_kernel<<<nw4 / 256, 256, 0, stream>>>(Wk, wkh, wkl, nw4);
  quant_fp4_split_kernel<<<nw4 / 256, 256, 0, stream>>>(Wv, wvh, wvl, nw4);
  quant_fp4_split_kernel<<<nw4 / 256, 256, 0, stream>>>(Wo, woh, wol, nw4);

  dim3 ggrid(Md / 32, HID / 128);  // (128, 16), 4 waves/block -> 32x32 tile/wave
  gemm_bt32_split<float><<<ggrid, 256, 0, stream>>>(xh, xl, wqh, wql, qb, Md, HID, HID);
  gemm_bt32_split<float><<<ggrid, 256, 0, stream>>>(xh, xl, wkh, wkl, kb, Md, HID, HID);
  gemm_bt32_split<float><<<ggrid, 256, 0, stream>>>(xh, xl, wvh, wvl, vb, Md, HID, HID);

  rope_kernel<<<(Md * NH * 32) / 256, 256, 0, stream>>>(qb, kb);

  attn_kernel<<<512, 256, 0, stream>>>(qb, kb, vb, ob);

  quant_fp4_split_kernel<<<nx4 / 256, 256, 0, stream>>>(ob, oh, ol, nx4);
  gemm_bt32_split<float><<<ggrid, 256, 0, stream>>>(oh, ol, woh, wol, out, Md, HID, HID);
}

// Round 4
// 2343.546 us; speedup vs baseline: 3.2694x; 3.2694x over previous
//
#include <hip/hip_runtime.h>
#include <hip/hip_bf16.h>

// Round 3: MFMA flash attention (f16 hi/lo split = effective fp32).
// Pipeline: quant_fp4_split -> split MFMA QKV gemms -> rope+split (head-major)
//           + V transpose+split -> MFMA flash attn -> quant -> final split GEMM.

typedef _Float16 f16;
typedef _Float16 f16x8 __attribute__((ext_vector_type(8)));
typedef float f32x4 __attribute__((ext_vector_type(4)));

static constexpr int Bd = 2, Sd = 2048, NH = 32, HD = 64, HID = 2048;
static constexpr int Md = Bd * Sd;   // 4096
static constexpr int LSTR = 72;      // LDS row stride (f16) for 64-col tiles

// ---------------- FP4 fake-quant (E2M1, block-16 absmax) ----------------
__device__ __forceinline__ float fp4_grid_round(float ay) {
  if (ay <= 0.25f) return 0.0f;
  if (ay <= 0.75f) return 0.5f;
  if (ay <= 1.25f) return 1.0f;
  if (ay <= 1.75f) return 1.5f;
  if (ay <= 2.5f)  return 2.0f;
  if (ay <= 3.5f)  return 3.0f;
  if (ay <= 5.0f)  return 4.0f;
  return 6.0f;
}

__global__ __launch_bounds__(256) void quant_fp4_split_kernel(const float* __restrict__ in,
                                                              f16* __restrict__ hi,
                                                              f16* __restrict__ lo, int n4) {
  int t = blockIdx.x * 256 + threadIdx.x;
  if (t >= n4) return;
  float v[4];
#pragma unroll
  for (int i = 0; i < 4; ++i) v[i] = in[4 * t + i];
  float a = fmaxf(fmaxf(fabsf(v[0]), fabsf(v[1])), fmaxf(fabsf(v[2]), fabsf(v[3])));
  a = fmaxf(a, __shfl_xor(a, 1));
  a = fmaxf(a, __shfl_xor(a, 2));
  float scale = (a == 0.0f) ? 1.0f : (a / 6.0f);
#pragma unroll
  for (int i = 0; i < 4; ++i) {
    float y = v[i] / scale;
    float g = fp4_grid_round(fabsf(y));
    float qv = copysignf(g * scale, y);
    f16 h = (f16)qv;
    hi[4 * t + i] = h;
    lo[4 * t + i] = (f16)(qv - (float)h);
  }
}

// ---------------- split GEMM: C[M,N] = A[M,K] * B[N,K]^T --------------------
template <typename OutT>
__global__ __launch_bounds__(256) void gemm_bt32_split(const f16* __restrict__ Ah,
                                                       const f16* __restrict__ Al,
                                                       const f16* __restrict__ Bh,
                                                       const f16* __restrict__ Bl,
                                                       OutT* __restrict__ C,
                                                       int Mm, int Nn, int Kk) {
  int wave = threadIdx.x >> 6, lane = threadIdx.x & 63;
  int qd = lane >> 4, c = lane & 15;
  int it = blockIdx.x;
  int jt = blockIdx.y * 4 + wave;
  size_t ra0 = (size_t)(it * 32 + c) * Kk, ra1 = ra0 + (size_t)16 * Kk;
  size_t rb0 = (size_t)(jt * 32 + c) * Kk, rb1 = rb0 + (size_t)16 * Kk;
  f32x4 acc[2][2];
#pragma unroll
  for (int i = 0; i < 2; ++i)
#pragma unroll
    for (int j = 0; j < 2; ++j) acc[i][j] = f32x4{0.f, 0.f, 0.f, 0.f};
  int ko = qd * 8;
  for (int kk = 0; kk < Kk; kk += 32) {
    f16x8 ah0 = *(const f16x8*)(Ah + ra0 + kk + ko);
    f16x8 ah1 = *(const f16x8*)(Ah + ra1 + kk + ko);
    f16x8 al0 = *(const f16x8*)(Al + ra0 + kk + ko);
    f16x8 al1 = *(const f16x8*)(Al + ra1 + kk + ko);
    f16x8 bh0 = *(const f16x8*)(Bh + rb0 + kk + ko);
    f16x8 bh1 = *(const f16x8*)(Bh + rb1 + kk + ko);
    f16x8 bl0 = *(const f16x8*)(Bl + rb0 + kk + ko);
    f16x8 bl1 = *(const f16x8*)(Bl + rb1 + kk + ko);
    acc[0][0] = __builtin_amdgcn_mfma_f32_16x16x32_f16(ah0, bh0, acc[0][0], 0, 0, 0);
    acc[0][1] = __builtin_amdgcn_mfma_f32_16x16x32_f16(ah0, bh1, acc[0][1], 0, 0, 0);
    acc[1][0] = __builtin_amdgcn_mfma_f32_16x16x32_f16(ah1, bh0, acc[1][0], 0, 0, 0);
    acc[1][1] = __builtin_amdgcn_mfma_f32_16x16x32_f16(ah1, bh1, acc[1][1], 0, 0, 0);
    acc[0][0] = __builtin_amdgcn_mfma_f32_16x16x32_f16(ah0, bl0, acc[0][0], 0, 0, 0);
    acc[0][1] = __builtin_amdgcn_mfma_f32_16x16x32_f16(ah0, bl1, acc[0][1], 0, 0, 0);
    acc[1][0] = __builtin_amdgcn_mfma_f32_16x16x32_f16(ah1, bl0, acc[1][0], 0, 0, 0);
    acc[1][1] = __builtin_amdgcn_mfma_f32_16x16x32_f16(ah1, bl1, acc[1][1], 0, 0, 0);
    acc[0][0] = __builtin_amdgcn_mfma_f32_16x16x32_f16(al0, bh0, acc[0][0], 0, 0, 0);
    acc[0][1] = __builtin_amdgcn_mfma_f32_16x16x32_f16(al0, bh1, acc[0][1], 0, 0, 0);
    acc[1][0] = __builtin_amdgcn_mfma_f32_16x16x32_f16(al1, bh0, acc[1][0], 0, 0, 0);
    acc[1][1] = __builtin_amdgcn_mfma_f32_16x16x32_f16(al1, bh1, acc[1][1], 0, 0, 0);
  }
#pragma unroll
  for (int ti = 0; ti < 2; ++ti)
#pragma unroll
    for (int tj = 0; tj < 2; ++tj) {
      size_t base = (size_t)(it * 32 + ti * 16 + qd * 4) * Nn + jt * 32 + tj * 16 + c;
#pragma unroll
      for (int r = 0; r < 4; ++r) C[base + (size_t)r * Nn] = (OutT)acc[ti][tj][r];
    }
}

// ---------------- RoPE + 0.125 scale + f16 split, head-major out ------------
// in: Q,K fp32 [b,s,h,d]; out: [head(b*32+h)][s][d] f16 hi/lo
__global__ __launch_bounds__(256) void rope_split_kernel(
    const float* __restrict__ Q, const float* __restrict__ K,
    f16* __restrict__ Qh, f16* __restrict__ Ql,
    f16* __restrict__ Kh, f16* __restrict__ Kl) {
  int t = blockIdx.x * 256 + threadIdx.x;   // 64*2048*32 threads
  int d2 = t & 31;
  int s = (t >> 5) & (Sd - 1);
  int head = t >> 16;
  int b = head >> 5, h = head & 31;
  float inv = expf(-0.2878231366242557f * (float)d2);  // 10000^(-d2/32)
  float ang = (float)s * inv;
  float sn, cs;
  sincosf(ang, &sn, &cs);
  size_t iin = (((size_t)(b * Sd + s)) * NH + h) * 64 + d2;
  size_t iout = (size_t)head * Sd * 64 + (size_t)s * 64 + d2;
  float q1 = Q[iin], q2 = Q[iin + 32];
  float k1 = K[iin], k2 = K[iin + 32];
  float qr1 = (q1 * cs - q2 * sn) * 0.125f;
  float qr2 = (q2 * cs + q1 * sn) * 0.125f;
  float kr1 = k1 * cs - k2 * sn;
  float kr2 = k2 * cs + k1 * sn;
  f16 v;
  v = (f16)qr1; Qh[iout] = v;      Ql[iout] = (f16)(qr1 - (float)v);
  v = (f16)qr2; Qh[iout + 32] = v; Ql[iout + 32] = (f16)(qr2 - (float)v);
  v = (f16)kr1; Kh[iout] = v;      Kl[iout] = (f16)(kr1 - (float)v);
  v = (f16)kr2; Kh[iout + 32] = v; Kl[iout + 32] = (f16)(kr2 - (float)v);
}

// ---------------- V transpose + split: Vt[head][d][s] -----------------------
__global__ __launch_bounds__(256) void v_split_t_kernel(const float* __restrict__ V,
                                                        f16* __restrict__ Vth,
                                                        f16* __restrict__ Vtl) {
  __shared__ float tile[64][65];
  int head = blockIdx.x;  // b*32+h
  int st = blockIdx.y;    // s tile of 64
  int b = head >> 5, h = head & 31;
  int tid = threadIdx.x;
  int r = tid >> 2, c4 = (tid & 3) * 16;
  const float* vp = V + (((size_t)(b * Sd + st * 64 + r)) * NH + h) * 64 + c4;
#pragma unroll
  for (int i = 0; i < 16; i += 4) {
    float4 v = *(const float4*)(vp + i);
    tile[r][c4 + i] = v.x; tile[r][c4 + i + 1] = v.y;
    tile[r][c4 + i + 2] = v.z; tile[r][c4 + i + 3] = v.w;
  }
  __syncthreads();
  int d = tid >> 2, s0 = (tid & 3) * 16;
  f16x8 hv[2], lv[2];
#pragma unroll
  for (int g = 0; g < 2; ++g)
#pragma unroll
    for (int i = 0; i < 8; ++i) {
      float v = tile[s0 + g * 8 + i][d];
      f16 hh = (f16)v;
      hv[g][i] = hh;
      lv[g][i] = (f16)(v - (float)hh);
    }
  size_t outb = (size_t)head * 64 * Sd + (size_t)d * Sd + st * 64 + s0;
  *(f16x8*)(Vth + outb) = hv[0];
  *(f16x8*)(Vth + outb + 8) = hv[1];
  *(f16x8*)(Vtl + outb) = lv[0];
  *(f16x8*)(Vtl + outb + 8) = lv[1];
}

// ---------------- MFMA flash attention --------------------------------------
// block = 4 waves = 64 q rows of one head; K/V tiles of 64; f16 hi/lo split.
__global__ __launch_bounds__(256) void attn_mfma_kernel(
    const f16* __restrict__ Qh, const f16* __restrict__ Ql,
    const f16* __restrict__ Kh, const f16* __restrict__ Kl,
    const f16* __restrict__ Vth, const f16* __restrict__ Vtl,
    float* __restrict__ O) {
  __shared__ f16 lds_kh[64 * LSTR];
  __shared__ f16 lds_kl[64 * LSTR];
  __shared__ f16 lds_vh[64 * LSTR];
  __shared__ f16 lds_vl[64 * LSTR];
  __shared__ f16 lds_ph[4 * 16 * LSTR];
  __shared__ f16 lds_pl[4 * 16 * LSTR];

  const int tid = threadIdx.x;
  const int wave = tid >> 6, lane = tid & 63;
  const int quad = lane >> 4, n16 = lane & 15;
  const int head = blockIdx.x;            // b*32+h
  const int qt = 31 - blockIdx.y;         // longest blocks first
  const int b = head >> 5, h = head & 31;

  const size_t hbase = (size_t)head * Sd * 64;   // [s][d] f16, per head
  const size_t vbase = (size_t)head * 64 * Sd;   // [d][s] f16, per head
  const int qrow_w = qt * 64 + wave * 16;

  // persistent Q fragments (A-layout)
  f16x8 qah[2], qal[2];
  {
    const f16* qp = Qh + hbase + (size_t)(qrow_w + n16) * 64 + quad * 8;
    const f16* qp2 = Ql + hbase + (size_t)(qrow_w + n16) * 64 + quad * 8;
    qah[0] = *(const f16x8*)(qp);
    qah[1] = *(const f16x8*)(qp + 32);
    qal[0] = *(const f16x8*)(qp2);
    qal[1] = *(const f16x8*)(qp2 + 32);
  }

  f32x4 acco[4];
#pragma unroll
  for (int t = 0; t < 4; ++t) acco[t] = f32x4{0.f, 0.f, 0.f, 0.f};
  float mrow[4], lrow[4];
#pragma unroll
  for (int r = 0; r < 4; ++r) { mrow[r] = -INFINITY; lrow[r] = 0.f; }

  const int sr = tid >> 2, ss = (tid & 3) * 16;   // staging: row, col-seg

  for (int kt = 0; kt <= qt; ++kt) {
    __syncthreads();
    {
      const f16* gk = Kh + hbase + (size_t)(kt * 64 + sr) * 64 + ss;
      const f16* gkl = Kl + hbase + (size_t)(kt * 64 + sr) * 64 + ss;
      const f16* gv = Vth + vbase + (size_t)sr * Sd + kt * 64 + ss;
      const f16* gvl = Vtl + vbase + (size_t)sr * Sd + kt * 64 + ss;
      int la = sr * LSTR + ss;
      *(f16x8*)&lds_kh[la] = *(const f16x8*)(gk);
      *(f16x8*)&lds_kh[la + 8] = *(const f16x8*)(gk + 8);
      *(f16x8*)&lds_kl[la] = *(const f16x8*)(gkl);
      *(f16x8*)&lds_kl[la + 8] = *(const f16x8*)(gkl + 8);
      *(f16x8*)&lds_vh[la] = *(const f16x8*)(gv);
      *(f16x8*)&lds_vh[la + 8] = *(const f16x8*)(gv + 8);
      *(f16x8*)&lds_vl[la] = *(const f16x8*)(gvl);
      *(f16x8*)&lds_vl[la + 8] = *(const f16x8*)(gvl + 8);
    }
    __syncthreads();

    // S = Q*K^T tile: 16 q-rows x 64 k-cols per wave
    f32x4 sacc[4];
#pragma unroll
    for (int t = 0; t < 4; ++t) sacc[t] = f32x4{0.f, 0.f, 0.f, 0.f};
#pragma unroll
    for (int t = 0; t < 4; ++t) {
      int off = (t * 16 + n16) * LSTR + quad * 8;
      f16x8 kb0h = *(const f16x8*)&lds_kh[off];
      f16x8 kb1h = *(const f16x8*)&lds_kh[off + 32];
      f16x8 kb0l = *(const f16x8*)&lds_kl[off];
      f16x8 kb1l = *(const f16x8*)&lds_kl[off + 32];
      sacc[t] = __builtin_amdgcn_mfma_f32_16x16x32_f16(qah[0], kb0h, sacc[t], 0, 0, 0);
      sacc[t] = __builtin_amdgcn_mfma_f32_16x16x32_f16(qah[1], kb1h, sacc[t], 0, 0, 0);
      sacc[t] = __builtin_amdgcn_mfma_f32_16x16x32_f16(qah[0], kb0l, sacc[t], 0, 0, 0);
      sacc[t] = __builtin_amdgcn_mfma_f32_16x16x32_f16(qah[1], kb1l, sacc[t], 0, 0, 0);
      sacc[t] = __builtin_amdgcn_mfma_f32_16x16x32_f16(qal[0], kb0h, sacc[t], 0, 0, 0);
      sacc[t] = __builtin_amdgcn_mfma_f32_16x16x32_f16(qal[1], kb1h, sacc[t], 0, 0, 0);
    }

    if (kt == qt) {  // diagonal tile: mask kcol > qrow
#pragma unroll
      for (int t = 0; t < 4; ++t)
#pragma unroll
        for (int r = 0; r < 4; ++r) {
          int kc = kt * 64 + t * 16 + n16;
          int qr = qrow_w + quad * 4 + r;
          if (kc > qr) sacc[t][r] = -INFINITY;
        }
    }

    // online softmax (row = quad*4+r, matching C-layout)
    float mt[4];
#pragma unroll
    for (int r = 0; r < 4; ++r)
      mt[r] = fmaxf(fmaxf(sacc[0][r], sacc[1][r]), fmaxf(sacc[2][r], sacc[3][r]));
#pragma unroll
    for (int i = 1; i < 16; i <<= 1)
#pragma unroll
      for (int r = 0; r < 4; ++r)
        mt[r] = fmaxf(mt[r], __shfl_xor(mt[r], i));
    float alpha[4], psum[4];
#pragma unroll
    for (int r = 0; r < 4; ++r) {
      float mn = fmaxf(mrow[r], mt[r]);
      alpha[r] = __expf(mrow[r] - mn);
      mrow[r] = mn;
      psum[r] = 0.f;
    }
#pragma unroll
    for (int t = 0; t < 4; ++t)
#pragma unroll
      for (int r = 0; r < 4; ++r) {
        float p = __expf(sacc[t][r] - mrow[r]);
        psum[r] += p;
        f16 ph = (f16)p;
        int addr = wave * 16 * LSTR + (quad * 4 + r) * LSTR + t * 16 + n16;
        lds_ph[addr] = ph;
        lds_pl[addr] = (f16)(p - (float)ph);
      }
#pragma unroll
    for (int i = 1; i < 16; i <<= 1)
#pragma unroll
      for (int r = 0; r < 4; ++r)
        psum[r] += __shfl_xor(psum[r], i);
#pragma unroll
    for (int r = 0; r < 4; ++r) lrow[r] = lrow[r] * alpha[r] + psum[r];
#pragma unroll
    for (int t = 0; t < 4; ++t)
#pragma unroll
      for (int r = 0; r < 4; ++r) acco[t][r] *= alpha[r];

    __asm__ volatile("s_waitcnt lgkmcnt(0)" ::: "memory");

    // O += P * V
    {
      int pbase = wave * 16 * LSTR + n16 * LSTR + quad * 8;
      f16x8 pa0h = *(const f16x8*)&lds_ph[pbase];
      f16x8 pa1h = *(const f16x8*)&lds_ph[pbase + 32];
      f16x8 pa0l = *(const f16x8*)&lds_pl[pbase];
      f16x8 pa1l = *(const f16x8*)&lds_pl[pbase + 32];
#pragma unroll
      for (int t = 0; t < 4; ++t) {
        int off = (t * 16 + n16) * LSTR + quad * 8;
        f16x8 vb0h = *(const f16x8*)&lds_vh[off];
        f16x8 vb1h = *(const f16x8*)&lds_vh[off + 32];
        f16x8 vb0l = *(const f16x8*)&lds_vl[off];
        f16x8 vb1l = *(const f16x8*)&lds_vl[off + 32];
        acco[t] = __builtin_amdgcn_mfma_f32_16x16x32_f16(pa0h, vb0h, acco[t], 0, 0, 0);
        acco[t] = __builtin_amdgcn_mfma_f32_16x16x32_f16(pa1h, vb1h, acco[t], 0, 0, 0);
        acco[t] = __builtin_amdgcn_mfma_f32_16x16x32_f16(pa0h, vb0l, acco[t], 0, 0, 0);
        acco[t] = __builtin_amdgcn_mfma_f32_16x16x32_f16(pa1h, vb1l, acco[t], 0, 0, 0);
        acco[t] = __builtin_amdgcn_mfma_f32_16x16x32_f16(pa0l, vb0h, acco[t], 0, 0, 0);
        acco[t] = __builtin_amdgcn_mfma_f32_16x16x32_f16(pa1l, vb1h, acco[t], 0, 0, 0);
      }
    }
  }

  // epilogue: O in [b,s,h,d] fp32
#pragma unroll
  for (int r = 0; r < 4; ++r) lrow[r] = 1.f / lrow[r];
#pragma unroll
  for (int t = 0; t < 4; ++t)
#pragma unroll
    for (int r = 0; r < 4; ++r) {
      int qr = qrow_w + quad * 4 + r;
      O[(((size_t)(b * Sd + qr)) * NH + h) * 64 + t * 16 + n16] = acco[t][r] * lrow[r];
    }
}

// ---------------- launch ----------------------------------------------------
extern "C" void kernel_launch(void* const* d_in, const int* in_sizes, int n_in,
                              void* d_out, int out_size, void* d_ws, size_t ws_size,
                              hipStream_t stream) {
  (void)in_sizes; (void)n_in; (void)out_size; (void)ws_size;
  const float* x  = (const float*)d_in[0];
  const float* Wq = (const float*)d_in[1];
  const float* Wk = (const float*)d_in[2];
  const float* Wv = (const float*)d_in[3];
  const float* Wo = (const float*)d_in[4];
  float* out = (float*)d_out;

  const size_t NX = (size_t)Md * HID;   // 8,388,608
  const size_t NW = (size_t)HID * HID;  // 4,194,304

  char* w = (char*)d_ws;
  size_t off = 0;
  auto alloc = [&](size_t bytes) { void* p = w + off; off += (bytes + 255) & ~(size_t)255; return p; };
  f16* xh  = (f16*)alloc(NX * 2);
  f16* xl  = (f16*)alloc(NX * 2);
  f16* wqh = (f16*)alloc(NW * 2);
  f16* wql = (f16*)alloc(NW * 2);
  f16* wkh = (f16*)alloc(NW * 2);
  f16* wkl = (f16*)alloc(NW * 2);
  f16* wvh = (f16*)alloc(NW * 2);
  f16* wvl = (f16*)alloc(NW * 2);
  f16* woh = (f16*)alloc(NW * 2);
  f16* wol = (f16*)alloc(NW * 2);
  float* qb = (float*)alloc(NX * 4);
  float* kb = (float*)alloc(NX * 4);
  float* vb = (float*)alloc(NX * 4);
  f16* qhs = (f16*)alloc(NX * 2);
  f16* qls = (f16*)alloc(NX * 2);
  f16* khs = (f16*)alloc(NX * 2);
  f16* kls = (f16*)alloc(NX * 2);
  // aliases (dead-after analysis):
  f16* vth = xh;            // x splits dead after QKV gemms
  f16* vtl = xl;
  float* ob = (float*)wqh;  // wq/wk splits dead after QKV gemms (NX*4 bytes = 4 x NW*2)
  f16* oh = (f16*)qb;       // qb dead after rope_split
  f16* ol = oh + NX;

  const int nx4 = (int)(NX / 4);
  const int nw4 = (int)(NW / 4);
  quant_fp4_split_kernel<<<nx4 / 256, 256, 0, stream>>>(x, xh, xl, nx4);
  quant_fp4_split_kernel<<<nw4 / 256, 256, 0, stream>>>(Wq, wqh, wql, nw4);
  quant_fp4_split_kernel<<<nw4 / 256, 256, 0, stream>>>(Wk, wkh, wkl, nw4);
  quant_fp4_split_kernel<<<nw4 / 256, 256, 0, stream>>>(Wv, wvh, wvl, nw4);
  quant_fp4_split_kernel<<<nw4 / 256, 256, 0, stream>>>(Wo, woh, wol, nw4);

  dim3 ggrid(Md / 32, HID / 128);
  gemm_bt32_split<float><<<ggrid, 256, 0, stream>>>(xh, xl, wqh, wql, qb, Md, HID, HID);
  gemm_bt32_split<float><<<ggrid, 256, 0, stream>>>(xh, xl, wkh, wkl, kb, Md, HID, HID);
  gemm_bt32_split<float><<<ggrid, 256, 0, stream>>>(xh, xl, wvh, wvl, vb, Md, HID, HID);

  rope_split_kernel<<<(64 * Sd * 32) / 256, 256, 0, stream>>>(qb, kb, qhs, qls, khs, kls);
  v_split_t_kernel<<<dim3(64, 32), 256, 0, stream>>>(vb, vth, vtl);

  attn_mfma_kernel<<<dim3(64, 32), 256, 0, stream>>>(qhs, qls, khs, kls, vth, vtl, ob);

  quant_fp4_split_kernel<<<nx4 / 256, 256, 0, stream>>>(ob, oh, ol, nx4);
  gemm_bt32_split<float><<<ggrid, 256, 0, stream>>>(oh, ol, woh, wol, out, Md, HID, HID);
}

// Round 5
// 825.475 us; speedup vs baseline: 9.2819x; 2.8390x over previous
//
#include <hip/hip_runtime.h>
#include <hip/hip_bf16.h>

// Round 4: m97-style LDS-staged split GEMM (128x128 tile, BK=32,
// global_load_lds width=16, 2-barrier K-loop). Attention/RoPE/quant unchanged.

typedef _Float16 f16;
typedef _Float16 f16x8 __attribute__((ext_vector_type(8)));
typedef float f32x4 __attribute__((ext_vector_type(4)));

static constexpr int Bd = 2, Sd = 2048, NH = 32, HD = 64, HID = 2048;
static constexpr int Md = Bd * Sd;   // 4096
static constexpr int LSTR = 72;      // LDS row stride (f16) for attn tiles

// ---------------- FP4 fake-quant (E2M1, block-16 absmax) ----------------
__device__ __forceinline__ float fp4_grid_round(float ay) {
  if (ay <= 0.25f) return 0.0f;
  if (ay <= 0.75f) return 0.5f;
  if (ay <= 1.25f) return 1.0f;
  if (ay <= 1.75f) return 1.5f;
  if (ay <= 2.5f)  return 2.0f;
  if (ay <= 3.5f)  return 3.0f;
  if (ay <= 5.0f)  return 4.0f;
  return 6.0f;
}

__global__ __launch_bounds__(256) void quant_fp4_split_kernel(const float* __restrict__ in,
                                                              f16* __restrict__ hi,
                                                              f16* __restrict__ lo, int n4) {
  int t = blockIdx.x * 256 + threadIdx.x;
  if (t >= n4) return;
  float v[4];
#pragma unroll
  for (int i = 0; i < 4; ++i) v[i] = in[4 * t + i];
  float a = fmaxf(fmaxf(fabsf(v[0]), fabsf(v[1])), fmaxf(fabsf(v[2]), fabsf(v[3])));
  a = fmaxf(a, __shfl_xor(a, 1));
  a = fmaxf(a, __shfl_xor(a, 2));
  float scale = (a == 0.0f) ? 1.0f : (a / 6.0f);
#pragma unroll
  for (int i = 0; i < 4; ++i) {
    float y = v[i] / scale;
    float g = fp4_grid_round(fabsf(y));
    float qv = copysignf(g * scale, y);
    f16 h = (f16)qv;
    hi[4 * t + i] = h;
    lo[4 * t + i] = (f16)(qv - (float)h);
  }
}

// ---------------- async global->LDS helper ----------------------------------
__device__ __forceinline__ void gl2lds16(const f16* g, f16* l) {
  __builtin_amdgcn_global_load_lds(
      (const __attribute__((address_space(1))) unsigned int*)g,
      (__attribute__((address_space(3))) unsigned int*)l, 16, 0, 0);
}

// ---------------- split GEMM: C[M,N] = A[M,K]*B[N,K]^T, 128x128 tile --------
// 256 thr = 4 waves (2x2), each wave 64x64 via 4x4 mfma_f32_16x16x32_f16
// tiles. A=Ah+Al, B=Bh+Bl; C ≈ Ah*Bh + Ah*Bl + Al*Bh (Al*Bl ~2^-22, dropped).
__global__ __launch_bounds__(256) void gemm128_split(const f16* __restrict__ Ah,
                                                     const f16* __restrict__ Al,
                                                     const f16* __restrict__ Bh,
                                                     const f16* __restrict__ Bl,
                                                     float* __restrict__ C,
                                                     int Nn, int Kk) {
  __shared__ f16 sAh[128 * 32];
  __shared__ f16 sAl[128 * 32];
  __shared__ f16 sBh[128 * 32];
  __shared__ f16 sBl[128 * 32];

  const int tid = threadIdx.x;
  const int w = tid >> 6, lane = tid & 63;
  const int wm = w & 1, wn = w >> 1;
  const int quad = lane >> 4, n16 = lane & 15;
  const int im = blockIdx.x, jn = blockIdx.y;

  // staging coords: per wave-instruction, 64 lanes fill 16 LDS rows (1024 B)
  const int srow = lane >> 2;          // 0..15
  const int schk = (lane & 3) * 8;     // f16 col offset of 16B chunk

  const size_t arow0 = (size_t)(im * 128) * Kk;
  const size_t brow0 = (size_t)(jn * 128) * Kk;

  f32x4 acc[4][4];
#pragma unroll
  for (int i = 0; i < 4; ++i)
#pragma unroll
    for (int j = 0; j < 4; ++j) acc[i][j] = f32x4{0.f, 0.f, 0.f, 0.f};

  for (int kk = 0; kk < Kk; kk += 32) {
    __syncthreads();
#pragma unroll
    for (int g = 0; g < 2; ++g) {
      int r = g * 64 + w * 16;                    // wave-uniform row base
      int lb = r * 32;                            // wave-uniform LDS base (f16)
      size_t go = (size_t)(r + srow) * Kk + kk + schk;  // per-lane global
      gl2lds16(Ah + arow0 + go, &sAh[lb]);
      gl2lds16(Al + arow0 + go, &sAl[lb]);
      gl2lds16(Bh + brow0 + go, &sBh[lb]);
      gl2lds16(Bl + brow0 + go, &sBl[lb]);
    }
    __syncthreads();

    f16x8 ah[4], al[4], bh[4], bl[4];
#pragma unroll
    for (int t = 0; t < 4; ++t) {
      int ao = (wm * 64 + t * 16 + n16) * 32 + quad * 8;
      int bo = (wn * 64 + t * 16 + n16) * 32 + quad * 8;
      ah[t] = *(const f16x8*)&sAh[ao];
      al[t] = *(const f16x8*)&sAl[ao];
      bh[t] = *(const f16x8*)&sBh[bo];
      bl[t] = *(const f16x8*)&sBl[bo];
    }
#pragma unroll
    for (int ti = 0; ti < 4; ++ti)
#pragma unroll
      for (int tj = 0; tj < 4; ++tj) {
        acc[ti][tj] = __builtin_amdgcn_mfma_f32_16x16x32_f16(ah[ti], bh[tj], acc[ti][tj], 0, 0, 0);
        acc[ti][tj] = __builtin_amdgcn_mfma_f32_16x16x32_f16(ah[ti], bl[tj], acc[ti][tj], 0, 0, 0);
        acc[ti][tj] = __builtin_amdgcn_mfma_f32_16x16x32_f16(al[ti], bh[tj], acc[ti][tj], 0, 0, 0);
      }
  }

#pragma unroll
  for (int ti = 0; ti < 4; ++ti)
#pragma unroll
    for (int tj = 0; tj < 4; ++tj) {
      size_t row = (size_t)(im * 128 + wm * 64 + ti * 16 + quad * 4);
      size_t col = jn * 128 + wn * 64 + tj * 16 + n16;
#pragma unroll
      for (int r = 0; r < 4; ++r)
        C[(row + r) * Nn + col] = acc[ti][tj][r];
    }
}

// ---------------- RoPE + 0.125 scale + f16 split, head-major out ------------
__global__ __launch_bounds__(256) void rope_split_kernel(
    const float* __restrict__ Q, const float* __restrict__ K,
    f16* __restrict__ Qh, f16* __restrict__ Ql,
    f16* __restrict__ Kh, f16* __restrict__ Kl) {
  int t = blockIdx.x * 256 + threadIdx.x;   // 64*2048*32 threads
  int d2 = t & 31;
  int s = (t >> 5) & (Sd - 1);
  int head = t >> 16;
  int b = head >> 5, h = head & 31;
  float inv = expf(-0.2878231366242557f * (float)d2);  // 10000^(-d2/32)
  float ang = (float)s * inv;
  float sn, cs;
  sincosf(ang, &sn, &cs);
  size_t iin = (((size_t)(b * Sd + s)) * NH + h) * 64 + d2;
  size_t iout = (size_t)head * Sd * 64 + (size_t)s * 64 + d2;
  float q1 = Q[iin], q2 = Q[iin + 32];
  float k1 = K[iin], k2 = K[iin + 32];
  float qr1 = (q1 * cs - q2 * sn) * 0.125f;
  float qr2 = (q2 * cs + q1 * sn) * 0.125f;
  float kr1 = k1 * cs - k2 * sn;
  float kr2 = k2 * cs + k1 * sn;
  f16 v;
  v = (f16)qr1; Qh[iout] = v;      Ql[iout] = (f16)(qr1 - (float)v);
  v = (f16)qr2; Qh[iout + 32] = v; Ql[iout + 32] = (f16)(qr2 - (float)v);
  v = (f16)kr1; Kh[iout] = v;      Kl[iout] = (f16)(kr1 - (float)v);
  v = (f16)kr2; Kh[iout + 32] = v; Kl[iout + 32] = (f16)(kr2 - (float)v);
}

// ---------------- V transpose + split: Vt[head][d][s] -----------------------
__global__ __launch_bounds__(256) void v_split_t_kernel(const float* __restrict__ V,
                                                        f16* __restrict__ Vth,
                                                        f16* __restrict__ Vtl) {
  __shared__ float tile[64][65];
  int head = blockIdx.x;
  int st = blockIdx.y;
  int b = head >> 5, h = head & 31;
  int tid = threadIdx.x;
  int r = tid >> 2, c4 = (tid & 3) * 16;
  const float* vp = V + (((size_t)(b * Sd + st * 64 + r)) * NH + h) * 64 + c4;
#pragma unroll
  for (int i = 0; i < 16; i += 4) {
    float4 v = *(const float4*)(vp + i);
    tile[r][c4 + i] = v.x; tile[r][c4 + i + 1] = v.y;
    tile[r][c4 + i + 2] = v.z; tile[r][c4 + i + 3] = v.w;
  }
  __syncthreads();
  int d = tid >> 2, s0 = (tid & 3) * 16;
  f16x8 hv[2], lv[2];
#pragma unroll
  for (int g = 0; g < 2; ++g)
#pragma unroll
    for (int i = 0; i < 8; ++i) {
      float v = tile[s0 + g * 8 + i][d];
      f16 hh = (f16)v;
      hv[g][i] = hh;
      lv[g][i] = (f16)(v - (float)hh);
    }
  size_t outb = (size_t)head * 64 * Sd + (size_t)d * Sd + st * 64 + s0;
  *(f16x8*)(Vth + outb) = hv[0];
  *(f16x8*)(Vth + outb + 8) = hv[1];
  *(f16x8*)(Vtl + outb) = lv[0];
  *(f16x8*)(Vtl + outb + 8) = lv[1];
}

// ---------------- MFMA flash attention --------------------------------------
__global__ __launch_bounds__(256) void attn_mfma_kernel(
    const f16* __restrict__ Qh, const f16* __restrict__ Ql,
    const f16* __restrict__ Kh, const f16* __restrict__ Kl,
    const f16* __restrict__ Vth, const f16* __restrict__ Vtl,
    float* __restrict__ O) {
  __shared__ f16 lds_kh[64 * LSTR];
  __shared__ f16 lds_kl[64 * LSTR];
  __shared__ f16 lds_vh[64 * LSTR];
  __shared__ f16 lds_vl[64 * LSTR];
  __shared__ f16 lds_ph[4 * 16 * LSTR];
  __shared__ f16 lds_pl[4 * 16 * LSTR];

  const int tid = threadIdx.x;
  const int wave = tid >> 6, lane = tid & 63;
  const int quad = lane >> 4, n16 = lane & 15;
  const int head = blockIdx.x;
  const int qt = 31 - blockIdx.y;
  const int b = head >> 5, h = head & 31;

  const size_t hbase = (size_t)head * Sd * 64;
  const size_t vbase = (size_t)head * 64 * Sd;
  const int qrow_w = qt * 64 + wave * 16;

  f16x8 qah[2], qal[2];
  {
    const f16* qp = Qh + hbase + (size_t)(qrow_w + n16) * 64 + quad * 8;
    const f16* qp2 = Ql + hbase + (size_t)(qrow_w + n16) * 64 + quad * 8;
    qah[0] = *(const f16x8*)(qp);
    qah[1] = *(const f16x8*)(qp + 32);
    qal[0] = *(const f16x8*)(qp2);
    qal[1] = *(const f16x8*)(qp2 + 32);
  }

  f32x4 acco[4];
#pragma unroll
  for (int t = 0; t < 4; ++t) acco[t] = f32x4{0.f, 0.f, 0.f, 0.f};
  float mrow[4], lrow[4];
#pragma unroll
  for (int r = 0; r < 4; ++r) { mrow[r] = -INFINITY; lrow[r] = 0.f; }

  const int sr = tid >> 2, ss = (tid & 3) * 16;

  for (int kt = 0; kt <= qt; ++kt) {
    __syncthreads();
    {
      const f16* gk = Kh + hbase + (size_t)(kt * 64 + sr) * 64 + ss;
      const f16* gkl = Kl + hbase + (size_t)(kt * 64 + sr) * 64 + ss;
      const f16* gv = Vth + vbase + (size_t)sr * Sd + kt * 64 + ss;
      const f16* gvl = Vtl + vbase + (size_t)sr * Sd + kt * 64 + ss;
      int la = sr * LSTR + ss;
      *(f16x8*)&lds_kh[la] = *(const f16x8*)(gk);
      *(f16x8*)&lds_kh[la + 8] = *(const f16x8*)(gk + 8);
      *(f16x8*)&lds_kl[la] = *(const f16x8*)(gkl);
      *(f16x8*)&lds_kl[la + 8] = *(const f16x8*)(gkl + 8);
      *(f16x8*)&lds_vh[la] = *(const f16x8*)(gv);
      *(f16x8*)&lds_vh[la + 8] = *(const f16x8*)(gv + 8);
      *(f16x8*)&lds_vl[la] = *(const f16x8*)(gvl);
      *(f16x8*)&lds_vl[la + 8] = *(const f16x8*)(gvl + 8);
    }
    __syncthreads();

    f32x4 sacc[4];
#pragma unroll
    for (int t = 0; t < 4; ++t) sacc[t] = f32x4{0.f, 0.f, 0.f, 0.f};
#pragma unroll
    for (int t = 0; t < 4; ++t) {
      int off = (t * 16 + n16) * LSTR + quad * 8;
      f16x8 kb0h = *(const f16x8*)&lds_kh[off];
      f16x8 kb1h = *(const f16x8*)&lds_kh[off + 32];
      f16x8 kb0l = *(const f16x8*)&lds_kl[off];
      f16x8 kb1l = *(const f16x8*)&lds_kl[off + 32];
      sacc[t] = __builtin_amdgcn_mfma_f32_16x16x32_f16(qah[0], kb0h, sacc[t], 0, 0, 0);
      sacc[t] = __builtin_amdgcn_mfma_f32_16x16x32_f16(qah[1], kb1h, sacc[t], 0, 0, 0);
      sacc[t] = __builtin_amdgcn_mfma_f32_16x16x32_f16(qah[0], kb0l, sacc[t], 0, 0, 0);
      sacc[t] = __builtin_amdgcn_mfma_f32_16x16x32_f16(qah[1], kb1l, sacc[t], 0, 0, 0);
      sacc[t] = __builtin_amdgcn_mfma_f32_16x16x32_f16(qal[0], kb0h, sacc[t], 0, 0, 0);
      sacc[t] = __builtin_amdgcn_mfma_f32_16x16x32_f16(qal[1], kb1h, sacc[t], 0, 0, 0);
    }

    if (kt == qt) {
#pragma unroll
      for (int t = 0; t < 4; ++t)
#pragma unroll
        for (int r = 0; r < 4; ++r) {
          int kc = kt * 64 + t * 16 + n16;
          int qr = qrow_w + quad * 4 + r;
          if (kc > qr) sacc[t][r] = -INFINITY;
        }
    }

    float mt[4];
#pragma unroll
    for (int r = 0; r < 4; ++r)
      mt[r] = fmaxf(fmaxf(sacc[0][r], sacc[1][r]), fmaxf(sacc[2][r], sacc[3][r]));
#pragma unroll
    for (int i = 1; i < 16; i <<= 1)
#pragma unroll
      for (int r = 0; r < 4; ++r)
        mt[r] = fmaxf(mt[r], __shfl_xor(mt[r], i));
    float alpha[4], psum[4];
#pragma unroll
    for (int r = 0; r < 4; ++r) {
      float mn = fmaxf(mrow[r], mt[r]);
      alpha[r] = __expf(mrow[r] - mn);
      mrow[r] = mn;
      psum[r] = 0.f;
    }
#pragma unroll
    for (int t = 0; t < 4; ++t)
#pragma unroll
      for (int r = 0; r < 4; ++r) {
        float p = __expf(sacc[t][r] - mrow[r]);
        psum[r] += p;
        f16 ph = (f16)p;
        int addr = wave * 16 * LSTR + (quad * 4 + r) * LSTR + t * 16 + n16;
        lds_ph[addr] = ph;
        lds_pl[addr] = (f16)(p - (float)ph);
      }
#pragma unroll
    for (int i = 1; i < 16; i <<= 1)
#pragma unroll
      for (int r = 0; r < 4; ++r)
        psum[r] += __shfl_xor(psum[r], i);
#pragma unroll
    for (int r = 0; r < 4; ++r) lrow[r] = lrow[r] * alpha[r] + psum[r];
#pragma unroll
    for (int t = 0; t < 4; ++t)
#pragma unroll
      for (int r = 0; r < 4; ++r) acco[t][r] *= alpha[r];

    __asm__ volatile("s_waitcnt lgkmcnt(0)" ::: "memory");

    {
      int pbase = wave * 16 * LSTR + n16 * LSTR + quad * 8;
      f16x8 pa0h = *(const f16x8*)&lds_ph[pbase];
      f16x8 pa1h = *(const f16x8*)&lds_ph[pbase + 32];
      f16x8 pa0l = *(const f16x8*)&lds_pl[pbase];
      f16x8 pa1l = *(const f16x8*)&lds_pl[pbase + 32];
#pragma unroll
      for (int t = 0; t < 4; ++t) {
        int off = (t * 16 + n16) * LSTR + quad * 8;
        f16x8 vb0h = *(const f16x8*)&lds_vh[off];
        f16x8 vb1h = *(const f16x8*)&lds_vh[off + 32];
        f16x8 vb0l = *(const f16x8*)&lds_vl[off];
        f16x8 vb1l = *(const f16x8*)&lds_vl[off + 32];
        acco[t] = __builtin_amdgcn_mfma_f32_16x16x32_f16(pa0h, vb0h, acco[t], 0, 0, 0);
        acco[t] = __builtin_amdgcn_mfma_f32_16x16x32_f16(pa1h, vb1h, acco[t], 0, 0, 0);
        acco[t] = __builtin_amdgcn_mfma_f32_16x16x32_f16(pa0h, vb0l, acco[t], 0, 0, 0);
        acco[t] = __builtin_amdgcn_mfma_f32_16x16x32_f16(pa1h, vb1l, acco[t], 0, 0, 0);
        acco[t] = __builtin_amdgcn_mfma_f32_16x16x32_f16(pa0l, vb0h, acco[t], 0, 0, 0);
        acco[t] = __builtin_amdgcn_mfma_f32_16x16x32_f16(pa1l, vb1h, acco[t], 0, 0, 0);
      }
    }
  }

#pragma unroll
  for (int r = 0; r < 4; ++r) lrow[r] = 1.f / lrow[r];
#pragma unroll
  for (int t = 0; t < 4; ++t)
#pragma unroll
    for (int r = 0; r < 4; ++r) {
      int qr = qrow_w + quad * 4 + r;
      O[(((size_t)(b * Sd + qr)) * NH + h) * 64 + t * 16 + n16] = acco[t][r] * lrow[r];
    }
}

// ---------------- launch ----------------------------------------------------
extern "C" void kernel_launch(void* const* d_in, const int* in_sizes, int n_in,
                              void* d_out, int out_size, void* d_ws, size_t ws_size,
                              hipStream_t stream) {
  (void)in_sizes; (void)n_in; (void)out_size; (void)ws_size;
  const float* x  = (const float*)d_in[0];
  const float* Wq = (const float*)d_in[1];
  const float* Wk = (const float*)d_in[2];
  const float* Wv = (const float*)d_in[3];
  const float* Wo = (const float*)d_in[4];
  float* out = (float*)d_out;

  const size_t NX = (size_t)Md * HID;   // 8,388,608
  const size_t NW = (size_t)HID * HID;  // 4,194,304

  char* w = (char*)d_ws;
  size_t off = 0;
  auto alloc = [&](size_t bytes) { void* p = w + off; off += (bytes + 255) & ~(size_t)255; return p; };
  f16* xh  = (f16*)alloc(NX * 2);
  f16* xl  = (f16*)alloc(NX * 2);
  f16* wqh = (f16*)alloc(NW * 2);
  f16* wql = (f16*)alloc(NW * 2);
  f16* wkh = (f16*)alloc(NW * 2);
  f16* wkl = (f16*)alloc(NW * 2);
  f16* wvh = (f16*)alloc(NW * 2);
  f16* wvl = (f16*)alloc(NW * 2);
  f16* woh = (f16*)alloc(NW * 2);
  f16* wol = (f16*)alloc(NW * 2);
  float* qb = (float*)alloc(NX * 4);
  float* kb = (float*)alloc(NX * 4);
  float* vb = (float*)alloc(NX * 4);
  f16* qhs = (f16*)alloc(NX * 2);
  f16* qls = (f16*)alloc(NX * 2);
  f16* khs = (f16*)alloc(NX * 2);
  f16* kls = (f16*)alloc(NX * 2);
  // aliases (dead-after analysis):
  f16* vth = xh;            // x splits dead after QKV gemms
  f16* vtl = xl;
  float* ob = (float*)wqh;  // wq/wk splits dead after QKV gemms
  f16* oh = (f16*)qb;       // qb dead after rope_split
  f16* ol = oh + NX;

  const int nx4 = (int)(NX / 4);
  const int nw4 = (int)(NW / 4);
  quant_fp4_split_kernel<<<nx4 / 256, 256, 0, stream>>>(x, xh, xl, nx4);
  quant_fp4_split_kernel<<<nw4 / 256, 256, 0, stream>>>(Wq, wqh, wql, nw4);
  quant_fp4_split_kernel<<<nw4 / 256, 256, 0, stream>>>(Wk, wkh, wkl, nw4);
  quant_fp4_split_kernel<<<nw4 / 256, 256, 0, stream>>>(Wv, wvh, wvl, nw4);
  quant_fp4_split_kernel<<<nw4 / 256, 256, 0, stream>>>(Wo, woh, wol, nw4);

  dim3 ggrid(Md / 128, HID / 128);  // (32, 16)
  gemm128_split<<<ggrid, 256, 0, stream>>>(xh, xl, wqh, wql, qb, HID, HID);
  gemm128_split<<<ggrid, 256, 0, stream>>>(xh, xl, wkh, wkl, kb, HID, HID);
  gemm128_split<<<ggrid, 256, 0, stream>>>(xh, xl, wvh, wvl, vb, HID, HID);

  rope_split_kernel<<<(64 * Sd * 32) / 256, 256, 0, stream>>>(qb, kb, qhs, qls, khs, kls);
  v_split_t_kernel<<<dim3(64, 32), 256, 0, stream>>>(vb, vth, vtl);

  attn_mfma_kernel<<<dim3(64, 32), 256, 0, stream>>>(qhs, qls, khs, kls, vth, vtl, ob);

  quant_fp4_split_kernel<<<nx4 / 256, 256, 0, stream>>>(ob, oh, ol, nx4);
  gemm128_split<<<ggrid, 256, 0, stream>>>(oh, ol, woh, wol, out, HID, HID);
}

// Round 6
// 791.282 us; speedup vs baseline: 9.6830x; 1.0432x over previous
//
#include <hip/hip_runtime.h>
#include <hip/hip_bf16.h>

// Round 5: (a) attention q-tile 128 (4 waves x 32 q-rows) -> 2x MFMA per
// barrier/staging; (b) RoPE+scale+f16-split fused into Q/K GEMM epilogues
// (rope_split kernel and qb/kb fp32 round-trip eliminated).

typedef _Float16 f16;
typedef _Float16 f16x8 __attribute__((ext_vector_type(8)));
typedef float f32x4 __attribute__((ext_vector_type(4)));

static constexpr int Bd = 2, Sd = 2048, NH = 32, HD = 64, HID = 2048;
static constexpr int Md = Bd * Sd;   // 4096
static constexpr int LSTR = 72;      // LDS row stride (f16) for attn tiles

// ---------------- FP4 fake-quant (E2M1, block-16 absmax) ----------------
__device__ __forceinline__ float fp4_grid_round(float ay) {
  if (ay <= 0.25f) return 0.0f;
  if (ay <= 0.75f) return 0.5f;
  if (ay <= 1.25f) return 1.0f;
  if (ay <= 1.75f) return 1.5f;
  if (ay <= 2.5f)  return 2.0f;
  if (ay <= 3.5f)  return 3.0f;
  if (ay <= 5.0f)  return 4.0f;
  return 6.0f;
}

__global__ __launch_bounds__(256) void quant_fp4_split_kernel(const float* __restrict__ in,
                                                              f16* __restrict__ hi,
                                                              f16* __restrict__ lo, int n4) {
  int t = blockIdx.x * 256 + threadIdx.x;
  if (t >= n4) return;
  float v[4];
#pragma unroll
  for (int i = 0; i < 4; ++i) v[i] = in[4 * t + i];
  float a = fmaxf(fmaxf(fabsf(v[0]), fabsf(v[1])), fmaxf(fabsf(v[2]), fabsf(v[3])));
  a = fmaxf(a, __shfl_xor(a, 1));
  a = fmaxf(a, __shfl_xor(a, 2));
  float scale = (a == 0.0f) ? 1.0f : (a / 6.0f);
#pragma unroll
  for (int i = 0; i < 4; ++i) {
    float y = v[i] / scale;
    float g = fp4_grid_round(fabsf(y));
    float qv = copysignf(g * scale, y);
    f16 h = (f16)qv;
    hi[4 * t + i] = h;
    lo[4 * t + i] = (f16)(qv - (float)h);
  }
}

// ---------------- async global->LDS helper ----------------------------------
__device__ __forceinline__ void gl2lds16(const f16* g, f16* l) {
  __builtin_amdgcn_global_load_lds(
      (const __attribute__((address_space(1))) unsigned int*)g,
      (__attribute__((address_space(3))) unsigned int*)l, 16, 0, 0);
}

// ---------------- split GEMM core macro-parts -------------------------------
// 256 thr = 4 waves (2x2), 128x128 tile, BK=32. C ≈ Ah*Bh + Ah*Bl + Al*Bh.

// K-loop shared by both GEMM variants (defines acc[4][4]).
#define GEMM128_BODY(Ah, Al, Bh, Bl, Kk)                                       \
  __shared__ f16 sAh[128 * 32];                                                \
  __shared__ f16 sAl[128 * 32];                                                \
  __shared__ f16 sBh[128 * 32];                                                \
  __shared__ f16 sBl[128 * 32];                                                \
  const int tid = threadIdx.x;                                                 \
  const int w = tid >> 6, lane = tid & 63;                                     \
  const int wm = w & 1, wn = w >> 1;                                           \
  const int quad = lane >> 4, n16 = lane & 15;                                 \
  const int im = blockIdx.x, jn = blockIdx.y;                                  \
  const int srow = lane >> 2;                                                  \
  const int schk = (lane & 3) * 8;                                             \
  const size_t arow0 = (size_t)(im * 128) * Kk;                                \
  const size_t brow0 = (size_t)(jn * 128) * Kk;                                \
  f32x4 acc[4][4];                                                             \
  _Pragma("unroll") for (int i = 0; i < 4; ++i)                                \
      _Pragma("unroll") for (int j = 0; j < 4; ++j)                            \
          acc[i][j] = f32x4{0.f, 0.f, 0.f, 0.f};                               \
  for (int kk = 0; kk < Kk; kk += 32) {                                        \
    __syncthreads();                                                           \
    _Pragma("unroll") for (int g = 0; g < 2; ++g) {                            \
      int r = g * 64 + w * 16;                                                 \
      int lb = r * 32;                                                         \
      size_t go = (size_t)(r + srow) * Kk + kk + schk;                         \
      gl2lds16(Ah + arow0 + go, &sAh[lb]);                                     \
      gl2lds16(Al + arow0 + go, &sAl[lb]);                                     \
      gl2lds16(Bh + brow0 + go, &sBh[lb]);                                     \
      gl2lds16(Bl + brow0 + go, &sBl[lb]);                                     \
    }                                                                          \
    __syncthreads();                                                           \
    f16x8 ah[4], al[4], bh[4], bl[4];                                          \
    _Pragma("unroll") for (int t = 0; t < 4; ++t) {                            \
      int ao = (wm * 64 + t * 16 + n16) * 32 + quad * 8;                       \
      int bo = (wn * 64 + t * 16 + n16) * 32 + quad * 8;                       \
      ah[t] = *(const f16x8*)&sAh[ao];                                         \
      al[t] = *(const f16x8*)&sAl[ao];                                         \
      bh[t] = *(const f16x8*)&sBh[bo];                                         \
      bl[t] = *(const f16x8*)&sBl[bo];                                         \
    }                                                                          \
    _Pragma("unroll") for (int ti = 0; ti < 4; ++ti)                           \
        _Pragma("unroll") for (int tj = 0; tj < 4; ++tj) {                     \
      acc[ti][tj] = __builtin_amdgcn_mfma_f32_16x16x32_f16(ah[ti], bh[tj],     \
                                                           acc[ti][tj], 0, 0, 0); \
      acc[ti][tj] = __builtin_amdgcn_mfma_f32_16x16x32_f16(ah[ti], bl[tj],     \
                                                           acc[ti][tj], 0, 0, 0); \
      acc[ti][tj] = __builtin_amdgcn_mfma_f32_16x16x32_f16(al[ti], bh[tj],     \
                                                           acc[ti][tj], 0, 0, 0); \
    }                                                                          \
  }

// plain variant: fp32 C, row-major [M,N]
__global__ __launch_bounds__(256) void gemm128_split(const f16* __restrict__ Ah,
                                                     const f16* __restrict__ Al,
                                                     const f16* __restrict__ Bh,
                                                     const f16* __restrict__ Bl,
                                                     float* __restrict__ C,
                                                     int Nn, int Kk) {
  GEMM128_BODY(Ah, Al, Bh, Bl, Kk)
#pragma unroll
  for (int ti = 0; ti < 4; ++ti)
#pragma unroll
    for (int tj = 0; tj < 4; ++tj) {
      size_t row = (size_t)(im * 128 + wm * 64 + ti * 16 + quad * 4);
      size_t col = jn * 128 + wn * 64 + tj * 16 + n16;
#pragma unroll
      for (int r = 0; r < 4; ++r)
        C[(row + r) * Nn + col] = acc[ti][tj][r];
    }
}

// Q/K variant: fused RoPE + qscale + f16 hi/lo split, head-major [head][s][d].
__global__ __launch_bounds__(256) void gemm128_qk(const f16* __restrict__ Ah,
                                                  const f16* __restrict__ Al,
                                                  const f16* __restrict__ Bh,
                                                  const f16* __restrict__ Bl,
                                                  f16* __restrict__ Oh,
                                                  f16* __restrict__ Ol,
                                                  float qscale, int Kk) {
  GEMM128_BODY(Ah, Al, Bh, Bl, Kk)
  // cols jn*128+wn*64.. = one head (64-wide); rows im*128.. = one b (128|2048)
  const int hidx = (jn * 128 + wn * 64) >> 6;   // 0..31
  const int b = im >> 4;                        // im*128 / 2048
  const size_t obase = (size_t)(b * 32 + hidx) * Sd * 64;
  const float inv0 = expf(-0.2878231366242557f * (float)n16);        // d2=n16
  const float inv1 = expf(-0.2878231366242557f * (float)(16 + n16)); // d2=16+n16
#pragma unroll
  for (int ti = 0; ti < 4; ++ti)
#pragma unroll
    for (int r = 0; r < 4; ++r) {
      int row = im * 128 + wm * 64 + ti * 16 + quad * 4 + r;
      int s = row & (Sd - 1);
#pragma unroll
      for (int tjp = 0; tjp < 2; ++tjp) {
        float inv = tjp ? inv1 : inv0;
        float sn, cs;
        sincosf((float)s * inv, &sn, &cs);
        float x1 = acc[ti][tjp][r] * qscale;
        float x2 = acc[ti][tjp + 2][r] * qscale;
        float o1 = x1 * cs - x2 * sn;   // d2
        float o2 = x2 * cs + x1 * sn;   // d2+32
        size_t i1 = obase + (size_t)s * 64 + tjp * 16 + n16;
        f16 hh;
        hh = (f16)o1; Oh[i1] = hh;      Ol[i1] = (f16)(o1 - (float)hh);
        hh = (f16)o2; Oh[i1 + 32] = hh; Ol[i1 + 32] = (f16)(o2 - (float)hh);
      }
    }
}

// ---------------- V transpose + split: Vt[head][d][s] -----------------------
__global__ __launch_bounds__(256) void v_split_t_kernel(const float* __restrict__ V,
                                                        f16* __restrict__ Vth,
                                                        f16* __restrict__ Vtl) {
  __shared__ float tile[64][65];
  int head = blockIdx.x;
  int st = blockIdx.y;
  int b = head >> 5, h = head & 31;
  int tid = threadIdx.x;
  int r = tid >> 2, c4 = (tid & 3) * 16;
  const float* vp = V + (((size_t)(b * Sd + st * 64 + r)) * NH + h) * 64 + c4;
#pragma unroll
  for (int i = 0; i < 16; i += 4) {
    float4 v = *(const float4*)(vp + i);
    tile[r][c4 + i] = v.x; tile[r][c4 + i + 1] = v.y;
    tile[r][c4 + i + 2] = v.z; tile[r][c4 + i + 3] = v.w;
  }
  __syncthreads();
  int d = tid >> 2, s0 = (tid & 3) * 16;
  f16x8 hv[2], lv[2];
#pragma unroll
  for (int g = 0; g < 2; ++g)
#pragma unroll
    for (int i = 0; i < 8; ++i) {
      float v = tile[s0 + g * 8 + i][d];
      f16 hh = (f16)v;
      hv[g][i] = hh;
      lv[g][i] = (f16)(v - (float)hh);
    }
  size_t outb = (size_t)head * 64 * Sd + (size_t)d * Sd + st * 64 + s0;
  *(f16x8*)(Vth + outb) = hv[0];
  *(f16x8*)(Vth + outb + 8) = hv[1];
  *(f16x8*)(Vtl + outb) = lv[0];
  *(f16x8*)(Vtl + outb + 8) = lv[1];
}

// ---------------- MFMA flash attention, 128 q-rows per block ----------------
// 4 waves x 32 q-rows; K/V tiles of 64; f16 hi/lo split everywhere.
__global__ __launch_bounds__(256) void attn_mfma_kernel(
    const f16* __restrict__ Qh, const f16* __restrict__ Ql,
    const f16* __restrict__ Kh, const f16* __restrict__ Kl,
    const f16* __restrict__ Vth, const f16* __restrict__ Vtl,
    float* __restrict__ O) {
  __shared__ f16 lds_kh[64 * LSTR];
  __shared__ f16 lds_kl[64 * LSTR];
  __shared__ f16 lds_vh[64 * LSTR];
  __shared__ f16 lds_vl[64 * LSTR];
  __shared__ f16 lds_ph[128 * LSTR];   // 4 waves * 32 rows
  __shared__ f16 lds_pl[128 * LSTR];

  const int tid = threadIdx.x;
  const int wave = tid >> 6, lane = tid & 63;
  const int quad = lane >> 4, n16 = lane & 15;
  const int head = blockIdx.x;
  const int qt = 15 - blockIdx.y;        // longest blocks first
  const int b = head >> 5, h = head & 31;

  const size_t hbase = (size_t)head * Sd * 64;
  const size_t vbase = (size_t)head * 64 * Sd;
  const int qrow_w = qt * 128 + wave * 32;

  // persistent Q fragments (A-layout), 2 row-tiles of 16
  f16x8 qah[2][2], qal[2][2];
#pragma unroll
  for (int ti = 0; ti < 2; ++ti) {
    const f16* qp = Qh + hbase + (size_t)(qrow_w + ti * 16 + n16) * 64 + quad * 8;
    const f16* qp2 = Ql + hbase + (size_t)(qrow_w + ti * 16 + n16) * 64 + quad * 8;
    qah[ti][0] = *(const f16x8*)(qp);
    qah[ti][1] = *(const f16x8*)(qp + 32);
    qal[ti][0] = *(const f16x8*)(qp2);
    qal[ti][1] = *(const f16x8*)(qp2 + 32);
  }

  f32x4 acco[2][4];
#pragma unroll
  for (int ti = 0; ti < 2; ++ti)
#pragma unroll
    for (int t = 0; t < 4; ++t) acco[ti][t] = f32x4{0.f, 0.f, 0.f, 0.f};
  float mrow[2][4], lrow[2][4];
#pragma unroll
  for (int ti = 0; ti < 2; ++ti)
#pragma unroll
    for (int r = 0; r < 4; ++r) { mrow[ti][r] = -INFINITY; lrow[ti][r] = 0.f; }

  const int sr = tid >> 2, ss = (tid & 3) * 16;
  const int nkt = 2 * qt + 2;

  for (int kt = 0; kt < nkt; ++kt) {
    __syncthreads();
    {
      const f16* gk = Kh + hbase + (size_t)(kt * 64 + sr) * 64 + ss;
      const f16* gkl = Kl + hbase + (size_t)(kt * 64 + sr) * 64 + ss;
      const f16* gv = Vth + vbase + (size_t)sr * Sd + kt * 64 + ss;
      const f16* gvl = Vtl + vbase + (size_t)sr * Sd + kt * 64 + ss;
      int la = sr * LSTR + ss;
      *(f16x8*)&lds_kh[la] = *(const f16x8*)(gk);
      *(f16x8*)&lds_kh[la + 8] = *(const f16x8*)(gk + 8);
      *(f16x8*)&lds_kl[la] = *(const f16x8*)(gkl);
      *(f16x8*)&lds_kl[la + 8] = *(const f16x8*)(gkl + 8);
      *(f16x8*)&lds_vh[la] = *(const f16x8*)(gv);
      *(f16x8*)&lds_vh[la + 8] = *(const f16x8*)(gv + 8);
      *(f16x8*)&lds_vl[la] = *(const f16x8*)(gvl);
      *(f16x8*)&lds_vl[la + 8] = *(const f16x8*)(gvl + 8);
    }
    __syncthreads();

    if (kt * 64 > qrow_w + 31) continue;  // fully-masked for this wave

    // S = Q*K^T: 32 q-rows x 64 k-cols per wave
    f32x4 sacc[2][4];
#pragma unroll
    for (int ti = 0; ti < 2; ++ti)
#pragma unroll
      for (int t = 0; t < 4; ++t) sacc[ti][t] = f32x4{0.f, 0.f, 0.f, 0.f};
#pragma unroll
    for (int t = 0; t < 4; ++t) {
      int off = (t * 16 + n16) * LSTR + quad * 8;
      f16x8 kb0h = *(const f16x8*)&lds_kh[off];
      f16x8 kb1h = *(const f16x8*)&lds_kh[off + 32];
      f16x8 kb0l = *(const f16x8*)&lds_kl[off];
      f16x8 kb1l = *(const f16x8*)&lds_kl[off + 32];
#pragma unroll
      for (int ti = 0; ti < 2; ++ti) {
        sacc[ti][t] = __builtin_amdgcn_mfma_f32_16x16x32_f16(qah[ti][0], kb0h, sacc[ti][t], 0, 0, 0);
        sacc[ti][t] = __builtin_amdgcn_mfma_f32_16x16x32_f16(qah[ti][1], kb1h, sacc[ti][t], 0, 0, 0);
        sacc[ti][t] = __builtin_amdgcn_mfma_f32_16x16x32_f16(qah[ti][0], kb0l, sacc[ti][t], 0, 0, 0);
        sacc[ti][t] = __builtin_amdgcn_mfma_f32_16x16x32_f16(qah[ti][1], kb1l, sacc[ti][t], 0, 0, 0);
        sacc[ti][t] = __builtin_amdgcn_mfma_f32_16x16x32_f16(qal[ti][0], kb0h, sacc[ti][t], 0, 0, 0);
        sacc[ti][t] = __builtin_amdgcn_mfma_f32_16x16x32_f16(qal[ti][1], kb1h, sacc[ti][t], 0, 0, 0);
      }
    }

    if (kt * 64 + 63 > qrow_w) {  // partial mask
#pragma unroll
      for (int ti = 0; ti < 2; ++ti)
#pragma unroll
        for (int t = 0; t < 4; ++t)
#pragma unroll
          for (int r = 0; r < 4; ++r) {
            int kc = kt * 64 + t * 16 + n16;
            int qr = qrow_w + ti * 16 + quad * 4 + r;
            if (kc > qr) sacc[ti][t][r] = -INFINITY;
          }
    }

    // online softmax per row-tile
#pragma unroll
    for (int ti = 0; ti < 2; ++ti) {
      float mt[4];
#pragma unroll
      for (int r = 0; r < 4; ++r)
        mt[r] = fmaxf(fmaxf(sacc[ti][0][r], sacc[ti][1][r]),
                      fmaxf(sacc[ti][2][r], sacc[ti][3][r]));
#pragma unroll
      for (int i = 1; i < 16; i <<= 1)
#pragma unroll
        for (int r = 0; r < 4; ++r)
          mt[r] = fmaxf(mt[r], __shfl_xor(mt[r], i));
      float alpha[4], psum[4];
#pragma unroll
      for (int r = 0; r < 4; ++r) {
        float mn = fmaxf(mrow[ti][r], mt[r]);
        alpha[r] = __expf(mrow[ti][r] - mn);
        mrow[ti][r] = mn;
        psum[r] = 0.f;
      }
#pragma unroll
      for (int t = 0; t < 4; ++t)
#pragma unroll
        for (int r = 0; r < 4; ++r) {
          float p = __expf(sacc[ti][t][r] - mrow[ti][r]);
          psum[r] += p;
          f16 ph = (f16)p;
          int addr = (wave * 32 + ti * 16 + quad * 4 + r) * LSTR + t * 16 + n16;
          lds_ph[addr] = ph;
          lds_pl[addr] = (f16)(p - (float)ph);
        }
#pragma unroll
      for (int i = 1; i < 16; i <<= 1)
#pragma unroll
        for (int r = 0; r < 4; ++r)
          psum[r] += __shfl_xor(psum[r], i);
#pragma unroll
      for (int r = 0; r < 4; ++r) lrow[ti][r] = lrow[ti][r] * alpha[r] + psum[r];
#pragma unroll
      for (int t = 0; t < 4; ++t)
#pragma unroll
        for (int r = 0; r < 4; ++r) acco[ti][t][r] *= alpha[r];
    }

    __asm__ volatile("s_waitcnt lgkmcnt(0)" ::: "memory");

    // O += P * V
    f16x8 pa0h[2], pa1h[2], pa0l[2], pa1l[2];
#pragma unroll
    for (int ti = 0; ti < 2; ++ti) {
      int pbase = (wave * 32 + ti * 16 + n16) * LSTR + quad * 8;
      pa0h[ti] = *(const f16x8*)&lds_ph[pbase];
      pa1h[ti] = *(const f16x8*)&lds_ph[pbase + 32];
      pa0l[ti] = *(const f16x8*)&lds_pl[pbase];
      pa1l[ti] = *(const f16x8*)&lds_pl[pbase + 32];
    }
#pragma unroll
    for (int t = 0; t < 4; ++t) {
      int off = (t * 16 + n16) * LSTR + quad * 8;
      f16x8 vb0h = *(const f16x8*)&lds_vh[off];
      f16x8 vb1h = *(const f16x8*)&lds_vh[off + 32];
      f16x8 vb0l = *(const f16x8*)&lds_vl[off];
      f16x8 vb1l = *(const f16x8*)&lds_vl[off + 32];
#pragma unroll
      for (int ti = 0; ti < 2; ++ti) {
        acco[ti][t] = __builtin_amdgcn_mfma_f32_16x16x32_f16(pa0h[ti], vb0h, acco[ti][t], 0, 0, 0);
        acco[ti][t] = __builtin_amdgcn_mfma_f32_16x16x32_f16(pa1h[ti], vb1h, acco[ti][t], 0, 0, 0);
        acco[ti][t] = __builtin_amdgcn_mfma_f32_16x16x32_f16(pa0h[ti], vb0l, acco[ti][t], 0, 0, 0);
        acco[ti][t] = __builtin_amdgcn_mfma_f32_16x16x32_f16(pa1h[ti], vb1l, acco[ti][t], 0, 0, 0);
        acco[ti][t] = __builtin_amdgcn_mfma_f32_16x16x32_f16(pa0l[ti], vb0h, acco[ti][t], 0, 0, 0);
        acco[ti][t] = __builtin_amdgcn_mfma_f32_16x16x32_f16(pa1l[ti], vb1h, acco[ti][t], 0, 0, 0);
      }
    }
  }

  // epilogue: O in [b,s,h,d] fp32
#pragma unroll
  for (int ti = 0; ti < 2; ++ti) {
#pragma unroll
    for (int r = 0; r < 4; ++r) {
      float rl = 1.f / lrow[ti][r];
      int qr = qrow_w + ti * 16 + quad * 4 + r;
#pragma unroll
      for (int t = 0; t < 4; ++t)
        O[(((size_t)(b * Sd + qr)) * NH + h) * 64 + t * 16 + n16] = acco[ti][t][r] * rl;
    }
  }
}

// ---------------- launch ----------------------------------------------------
extern "C" void kernel_launch(void* const* d_in, const int* in_sizes, int n_in,
                              void* d_out, int out_size, void* d_ws, size_t ws_size,
                              hipStream_t stream) {
  (void)in_sizes; (void)n_in; (void)out_size; (void)ws_size;
  const float* x  = (const float*)d_in[0];
  const float* Wq = (const float*)d_in[1];
  const float* Wk = (const float*)d_in[2];
  const float* Wv = (const float*)d_in[3];
  const float* Wo = (const float*)d_in[4];
  float* out = (float*)d_out;

  const size_t NX = (size_t)Md * HID;   // 8,388,608
  const size_t NW = (size_t)HID * HID;  // 4,194,304

  char* w = (char*)d_ws;
  size_t off = 0;
  auto alloc = [&](size_t bytes) { void* p = w + off; off += (bytes + 255) & ~(size_t)255; return p; };
  f16* xh  = (f16*)alloc(NX * 2);
  f16* xl  = (f16*)alloc(NX * 2);
  f16* wqh = (f16*)alloc(NW * 2);
  f16* wql = (f16*)alloc(NW * 2);
  f16* wkh = (f16*)alloc(NW * 2);
  f16* wkl = (f16*)alloc(NW * 2);
  f16* wvh = (f16*)alloc(NW * 2);
  f16* wvl = (f16*)alloc(NW * 2);
  f16* woh = (f16*)alloc(NW * 2);
  f16* wol = (f16*)alloc(NW * 2);
  float* vb = (float*)alloc(NX * 4);
  f16* qhs = (f16*)alloc(NX * 2);
  f16* qls = (f16*)alloc(NX * 2);
  f16* khs = (f16*)alloc(NX * 2);
  f16* kls = (f16*)alloc(NX * 2);
  // aliases (dead-after analysis):
  f16* vth = xh;            // x splits dead after QKV gemms; vth/vtl live for attn
  f16* vtl = xl;
  float* ob = (float*)wqh;  // wq/wk splits dead after Q/K gemms (4*NW*2 = NX*4 B)
  f16* oh = qhs;            // q splits dead after attn
  f16* ol = qls;

  const int nx4 = (int)(NX / 4);
  const int nw4 = (int)(NW / 4);
  quant_fp4_split_kernel<<<nx4 / 256, 256, 0, stream>>>(x, xh, xl, nx4);
  quant_fp4_split_kernel<<<nw4 / 256, 256, 0, stream>>>(Wq, wqh, wql, nw4);
  quant_fp4_split_kernel<<<nw4 / 256, 256, 0, stream>>>(Wk, wkh, wkl, nw4);
  quant_fp4_split_kernel<<<nw4 / 256, 256, 0, stream>>>(Wv, wvh, wvl, nw4);
  quant_fp4_split_kernel<<<nw4 / 256, 256, 0, stream>>>(Wo, woh, wol, nw4);

  dim3 ggrid(Md / 128, HID / 128);  // (32, 16)
  gemm128_qk<<<ggrid, 256, 0, stream>>>(xh, xl, wqh, wql, qhs, qls, 0.125f, HID);
  gemm128_qk<<<ggrid, 256, 0, stream>>>(xh, xl, wkh, wkl, khs, kls, 1.0f, HID);
  gemm128_split<<<ggrid, 256, 0, stream>>>(xh, xl, wvh, wvl, vb, HID, HID);

  v_split_t_kernel<<<dim3(64, 32), 256, 0, stream>>>(vb, vth, vtl);

  attn_mfma_kernel<<<dim3(64, 16), 256, 0, stream>>>(qhs, qls, khs, kls, vth, vtl, ob);

  quant_fp4_split_kernel<<<nx4 / 256, 256, 0, stream>>>(ob, oh, ol, nx4);
  gemm128_split<<<ggrid, 256, 0, stream>>>(oh, ol, woh, wol, out, HID, HID);
}